// Round 6
// baseline (592.659 us; speedup 1.0000x reference)
//
#include <hip/hip_runtime.h>

#define N_PTS 100000
#define NT_STRIDE 100096            // padded row count for nbrsT
#define NK 27
#define NKP 28                      // k slots incl. dummy zero slot k=27
#define TOTAL (N_PTS * 64)          // 6400000
#define NB_CONV 1564                // grid: 1564 blocks * 64 rows

typedef short bf16x8 __attribute__((ext_vector_type(8)));   // 8 bf16 in 4 VGPRs
typedef float f32x4 __attribute__((ext_vector_type(4)));
typedef unsigned short u16x8 __attribute__((ext_vector_type(8)));

__device__ __forceinline__ unsigned short f2bf(float f) {
    unsigned u = __builtin_bit_cast(unsigned, f);
    u += 0x7fffu + ((u >> 16) & 1u);           // round-to-nearest-even
    return (unsigned short)(u >> 16);
}
__device__ __forceinline__ float bf2f(unsigned short u) {
    return __builtin_bit_cast(float, ((unsigned)u) << 16);
}

// ---------------- cast feats -> bf16, plus zeroed pad row at index N_PTS ----------------
__global__ void cast_in_k(const float* __restrict__ feats, unsigned short* __restrict__ xb) {
    int t = blockIdx.x * 256 + threadIdx.x;
    if (t >= (N_PTS + 1) * 8) return;
    int i = t * 8;
    u16x8 o;
    if (i < TOTAL) {
        f32x4 v0 = ((const f32x4*)(feats + i))[0];
        f32x4 v1 = ((const f32x4*)(feats + i))[1];
#pragma unroll
        for (int j = 0; j < 4; ++j) { o[j] = f2bf(v0[j]); o[4 + j] = f2bf(v1[j]); }
    } else {
#pragma unroll
        for (int j = 0; j < 8; ++j) o[j] = 0;
    }
    *(u16x8*)(xb + i) = o;
}

// ---------------- transpose rulebook: nbrsT[k][n] = nbrs[n][k]; k=27 row & pad rows -> N_PTS ----------------
__global__ void tr_nbrs_k(const int* __restrict__ nbrs, int* __restrict__ nbrsT) {
    __shared__ int tile[64 * 28];
    const int n0 = blockIdx.x * 64;
    const int t = threadIdx.x;
    const int base = n0 * 27;
    for (int i = t; i < 1728; i += 256) {
        int v = (base + i < N_PTS * 27) ? nbrs[base + i] : N_PTS;
        int r = i / 27, c = i - r * 27;
        tile[r * 28 + c] = v;
    }
    __syncthreads();
    for (int i = t; i < 1728; i += 256) {
        int k = i >> 6, j = i & 63;                        // k 0..26
        nbrsT[(size_t)k * NT_STRIDE + n0 + j] = tile[j * 28 + k];
    }
    for (int i = t; i < 64; i += 256)                      // dummy k=27 row -> pad
        nbrsT[(size_t)27 * NT_STRIDE + n0 + i] = N_PTS;
}

// ---------------- pack W -> bf16 MFMA-B-fragment order, 28 k-slots/conv (k=27 zeroed) ----------------
// Wp layout: [conv][k(28)][kk][cb][lane][8]; frag elem j is B[c = kk*32+(lane>>4)*8+j, d = cb*16+(lane&15)]
__global__ void pack_w_k(const float* __restrict__ W, unsigned short* __restrict__ Wp) {
    int o = blockIdx.x * 256 + threadIdx.x;
    if (o >= 4 * NKP * 4096) return;
    int conv = o / (NKP * 4096);
    int r = o - conv * (NKP * 4096);
    int k = r >> 12;
    if (k == 27) { Wp[o] = 0; return; }
    int r2 = r & 4095;
    int frag = r2 >> 9;
    int kk = frag >> 2, cb = frag & 3;
    int lane = (r2 >> 3) & 63;
    int j = r2 & 7;
    int c = kk * 32 + (lane >> 4) * 8 + j;
    int d = cb * 16 + (lane & 15);
    Wp[o] = f2bf(W[(size_t)(conv * NK + k) * 4096 + c * 64 + d]);
}

// ---------------- gather-GEMM conv, K-split across wave pairs ----------------
// FUSED=1: input rows are RAW previous-conv output; apply bn(scale,shift)+relu in-register
// after gather (pad row idx==N_PTS forced to zero via select). Numerically identical to
// the materialized bn_relu_cast path. Stats for the NEXT bn accumulated via atomicAdd.
template <int FUSED>
__global__ __launch_bounds__(256, 4) void conv_k(
    const unsigned short* __restrict__ xin,    // [N_PTS+1][64] bf16 (raw if FUSED)
    const int* __restrict__ nbrsT,             // [28][NT_STRIDE]
    const unsigned short* __restrict__ Wp,     // packed fragments for this conv (28 k-slots)
    unsigned short* __restrict__ yout,         // [N_PTS(+1)][64] bf16 raw conv output
    const float* __restrict__ gpart_in,        // [128] sum/sumsq of xin (FUSED only)
    const float* __restrict__ gamma,           // [64] (FUSED only)
    const float* __restrict__ beta,            // [64] (FUSED only)
    float* __restrict__ gpart_out)             // [128] accumulated sum/sumsq of yout
{
    const int tid = threadIdx.x;
    const int lane = tid & 63;
    const int wave = tid >> 6;
    const int l15 = lane & 15;
    const int lgrp = lane >> 4;
    const int h = wave & 1;                    // rowhalf
    const int kh = wave >> 1;                  // khalf
    const int wave_row = blockIdx.x * 64 + h * 32;
    const int r0 = wave_row + l15;             // < NT_STRIDE always
    const int r1 = r0 + 16;
    const int k0 = kh * 14;                    // kh=0: k 0..13 ; kh=1: k 14..27 (27 = zeros)

    // BN scale/shift for this lane's 16 input channels (half: 0 -> ch lgrp*8.., 1 -> 32+lgrp*8..)
    float sc[2][8], sh[2][8];
    if (FUSED) {
        const float invN = 1.0f / (float)N_PTS;
#pragma unroll
        for (int half = 0; half < 2; ++half) {
            int cbase = half * 32 + lgrp * 8;
#pragma unroll
            for (int e = 0; e < 8; ++e) {
                int c = cbase + e;
                float S = gpart_in[c], S2 = gpart_in[64 + c];
                float mu = S * invN;
                float var = S2 * invN - mu * mu;
                float s = gamma[c] * rsqrtf(var + 1e-4f);
                sc[half][e] = s;
                sh[half][e] = beta[c] - mu * s;
            }
        }
    }

    f32x4 acc[2][4];
#pragma unroll
    for (int m = 0; m < 2; ++m)
#pragma unroll
        for (int cb = 0; cb < 4; ++cb) acc[m][cb] = (f32x4)0.f;

    const bf16x8* wp = (const bf16x8*)Wp;

    // gather + optional bn-relu apply for one row: fills dst[0] (ch half 0), dst[1] (ch half 1)
    auto ldrow = [&](int idx, bf16x8* dst) {
        const bf16x8* p = (const bf16x8*)(xin + (size_t)idx * 64);
        bf16x8 a0 = p[lgrp];
        bf16x8 a1 = p[4 + lgrp];
        if (FUSED) {
            bool ok = (idx != N_PTS);
            u16x8 u0 = __builtin_bit_cast(u16x8, a0);
            u16x8 u1 = __builtin_bit_cast(u16x8, a1);
            u16x8 o0, o1;
#pragma unroll
            for (int e = 0; e < 8; ++e) {
                o0[e] = f2bf(fmaxf(bf2f(u0[e]) * sc[0][e] + sh[0][e], 0.f));
                o1[e] = f2bf(fmaxf(bf2f(u1[e]) * sc[1][e] + sh[1][e], 0.f));
            }
            bf16x8 z = (bf16x8)(short)0;
            a0 = ok ? __builtin_bit_cast(bf16x8, o0) : z;
            a1 = ok ? __builtin_bit_cast(bf16x8, o1) : z;
        }
        dst[0] = a0;
        dst[1] = a1;
    };

    // idx pipeline: window of 4 per row-half (nontemporal: single-use stream)
    int id0[4], id1[4];
#pragma unroll
    for (int s = 0; s < 4; ++s) {
        id0[s] = __builtin_nontemporal_load(nbrsT + (size_t)(k0 + s) * NT_STRIDE + r0);
        id1[s] = __builtin_nontemporal_load(nbrsT + (size_t)(k0 + s) * NT_STRIDE + r1);
    }
    // A pipeline: 3 stages x 4 frags ([0]=row0 ch0-31, [1]=row0 ch32-63, [2]=row1 ch0-31, [3]=row1 ch32-63)
    bf16x8 apf[3][4];
#pragma unroll
    for (int s = 0; s < 2; ++s) {
        ldrow(id0[s], &apf[s][0]);
        ldrow(id1[s], &apf[s][2]);
    }

#pragma unroll
    for (int s = 0; s < 14; ++s) {
        if (s + 4 < 14) {                      // idx prefetch (coalesced)
            id0[s & 3] = __builtin_nontemporal_load(nbrsT + (size_t)(k0 + s + 4) * NT_STRIDE + r0);
            id1[s & 3] = __builtin_nontemporal_load(nbrsT + (size_t)(k0 + s + 4) * NT_STRIDE + r1);
        }
        if (s + 2 < 14) {                      // A-gather prefetch for s+2
            const int j = (s + 2) & 3;
            const int st2 = (s + 2) % 3;
            ldrow(id0[j], &apf[st2][0]);
            ldrow(id1[j], &apf[st2][2]);
        }
        const int st = s % 3;
        const bf16x8* wk = wp + (size_t)(k0 + s) * 512 + lane;
        {   // kk = 0 (c 0..31)
            bf16x8 b0 = wk[0], b1 = wk[64], b2 = wk[128], b3 = wk[192];
            acc[0][0] = __builtin_amdgcn_mfma_f32_16x16x32_bf16(apf[st][0], b0, acc[0][0], 0, 0, 0);
            acc[1][0] = __builtin_amdgcn_mfma_f32_16x16x32_bf16(apf[st][2], b0, acc[1][0], 0, 0, 0);
            acc[0][1] = __builtin_amdgcn_mfma_f32_16x16x32_bf16(apf[st][0], b1, acc[0][1], 0, 0, 0);
            acc[1][1] = __builtin_amdgcn_mfma_f32_16x16x32_bf16(apf[st][2], b1, acc[1][1], 0, 0, 0);
            acc[0][2] = __builtin_amdgcn_mfma_f32_16x16x32_bf16(apf[st][0], b2, acc[0][2], 0, 0, 0);
            acc[1][2] = __builtin_amdgcn_mfma_f32_16x16x32_bf16(apf[st][2], b2, acc[1][2], 0, 0, 0);
            acc[0][3] = __builtin_amdgcn_mfma_f32_16x16x32_bf16(apf[st][0], b3, acc[0][3], 0, 0, 0);
            acc[1][3] = __builtin_amdgcn_mfma_f32_16x16x32_bf16(apf[st][2], b3, acc[1][3], 0, 0, 0);
        }
        {   // kk = 1 (c 32..63)
            bf16x8 b0 = wk[256], b1 = wk[320], b2 = wk[384], b3 = wk[448];
            acc[0][0] = __builtin_amdgcn_mfma_f32_16x16x32_bf16(apf[st][1], b0, acc[0][0], 0, 0, 0);
            acc[1][0] = __builtin_amdgcn_mfma_f32_16x16x32_bf16(apf[st][3], b0, acc[1][0], 0, 0, 0);
            acc[0][1] = __builtin_amdgcn_mfma_f32_16x16x32_bf16(apf[st][1], b1, acc[0][1], 0, 0, 0);
            acc[1][1] = __builtin_amdgcn_mfma_f32_16x16x32_bf16(apf[st][3], b1, acc[1][1], 0, 0, 0);
            acc[0][2] = __builtin_amdgcn_mfma_f32_16x16x32_bf16(apf[st][1], b2, acc[0][2], 0, 0, 0);
            acc[1][2] = __builtin_amdgcn_mfma_f32_16x16x32_bf16(apf[st][3], b2, acc[1][2], 0, 0, 0);
            acc[0][3] = __builtin_amdgcn_mfma_f32_16x16x32_bf16(apf[st][1], b3, acc[0][3], 0, 0, 0);
            acc[1][3] = __builtin_amdgcn_mfma_f32_16x16x32_bf16(apf[st][3], b3, acc[1][3], 0, 0, 0);
        }
    }

    // ---- K-half reduction through LDS f32 tile (row stride 68 keeps 16B alignment) ----
    __shared__ __align__(16) float ytile[64 * 68];
    __shared__ __align__(16) float sred[4][128];

    if (kh == 0) {
#pragma unroll
        for (int m = 0; m < 2; ++m)
#pragma unroll
            for (int cb = 0; cb < 4; ++cb)
#pragma unroll
                for (int r = 0; r < 4; ++r)
                    ytile[(h * 32 + m * 16 + lgrp * 4 + r) * 68 + cb * 16 + l15] = acc[m][cb][r];
    }
    __syncthreads();
    if (kh == 1) {
#pragma unroll
        for (int m = 0; m < 2; ++m)
#pragma unroll
            for (int cb = 0; cb < 4; ++cb)
#pragma unroll
                for (int r = 0; r < 4; ++r)
                    ytile[(h * 32 + m * 16 + lgrp * 4 + r) * 68 + cb * 16 + l15] += acc[m][cb][r];
    }
    __syncthreads();

    // ---- coalesced read-out -> nontemporal bf16 y store + per-channel sum/sumsq ----
    const int row = tid >> 2;                  // 0..63
    const int colb = (tid & 3) * 16;           // 0,16,32,48
    f32x4 v[4];
#pragma unroll
    for (int j = 0; j < 4; ++j) v[j] = *(const f32x4*)&ytile[row * 68 + colb + 4 * j];

    const int grow = blockIdx.x * 64 + row;
    if (grow < N_PTS) {
        u16x8 o0, o1;
#pragma unroll
        for (int j = 0; j < 4; ++j) { o0[j] = f2bf(v[0][j]); o0[4 + j] = f2bf(v[1][j]); }
#pragma unroll
        for (int j = 0; j < 4; ++j) { o1[j] = f2bf(v[2][j]); o1[4 + j] = f2bf(v[3][j]); }
        __builtin_nontemporal_store(o0, (u16x8*)(yout + (size_t)grow * 64 + colb));
        __builtin_nontemporal_store(o1, (u16x8*)(yout + (size_t)grow * 64 + colb + 8));
    }

    f32x4 sv[4], s2v[4];
#pragma unroll
    for (int j = 0; j < 4; ++j) { sv[j] = v[j]; s2v[j] = v[j] * v[j]; }
#pragma unroll
    for (int off = 4; off < 64; off <<= 1) {
#pragma unroll
        for (int j = 0; j < 4; ++j) {
#pragma unroll
            for (int e = 0; e < 4; ++e) {
                sv[j][e]  += __shfl_xor(sv[j][e],  off);
                s2v[j][e] += __shfl_xor(s2v[j][e], off);
            }
        }
    }
    if (lane < 4) {
#pragma unroll
        for (int j = 0; j < 4; ++j) {
            *(f32x4*)&sred[wave][lane * 16 + 4 * j]      = sv[j];
            *(f32x4*)&sred[wave][64 + lane * 16 + 4 * j] = s2v[j];
        }
    }
    __syncthreads();
    if (tid < 128) {
        float p = sred[0][tid] + sred[1][tid] + sred[2][tid] + sred[3][tid];
        atomicAdd(&gpart_out[tid], p);
    }
}

// ---------------- BN(inline stats) + residual + ReLU -> f32 out (+ bf16 for next conv) ----------------
__global__ void bn_fuse_k(const unsigned short* __restrict__ yraw,
                          const float* __restrict__ gpart,
                          const float* __restrict__ gamma,
                          const float* __restrict__ beta,
                          const float* __restrict__ res,
                          float* __restrict__ xout,
                          unsigned short* __restrict__ xb, int writeBf) {
    int t = blockIdx.x * 256 + threadIdx.x;
    if (t >= TOTAL / 8) return;
    int i = t * 8;
    int c0 = i & 63;
    u16x8 v = __builtin_nontemporal_load((const u16x8*)(yraw + i));
    f32x4 q0 = __builtin_nontemporal_load((const f32x4*)(res + i));
    f32x4 q1 = __builtin_nontemporal_load((const f32x4*)(res + i) + 1);

    const float invN = 1.0f / (float)N_PTS;
    float sc[8], sh[8];
#pragma unroll
    for (int j = 0; j < 8; ++j) {
        int c = c0 + j;
        float S = gpart[c], S2 = gpart[64 + c];
        float mu = S * invN;
        float var = S2 * invN - mu * mu;
        float s = gamma[c] * rsqrtf(var + 1e-4f);
        sc[j] = s;
        sh[j] = beta[c] - mu * s;
    }
    f32x4 o0, o1;
#pragma unroll
    for (int j = 0; j < 4; ++j) {
        o0[j] = fmaxf(bf2f(v[j])     * sc[j]     + sh[j]     + q0[j], 0.f);
        o1[j] = fmaxf(bf2f(v[4 + j]) * sc[4 + j] + sh[4 + j] + q1[j], 0.f);
    }
    __builtin_nontemporal_store(o0, (f32x4*)(xout + i));
    __builtin_nontemporal_store(o1, (f32x4*)(xout + i) + 1);
    if (writeBf) {
        u16x8 o;
#pragma unroll
        for (int j = 0; j < 4; ++j) { o[j] = f2bf(o0[j]); o[4 + j] = f2bf(o1[j]); }
        *(u16x8*)(xb + i) = o;
    }
}

extern "C" void kernel_launch(void* const* d_in, const int* in_sizes, int n_in,
                              void* d_out, int out_size, void* d_ws, size_t ws_size,
                              hipStream_t stream) {
    const float* feats = (const float*)d_in[0];
    const int*   nbrs  = (const int*)d_in[1];
    const float* W     = (const float*)d_in[2];
    const float* gamma = (const float*)d_in[3];
    const float* beta  = (const float*)d_in[4];
    float* out = (float*)d_out;

    char* ws = (char*)d_ws;
    unsigned short* xb    = (unsigned short*)ws;              // 12,800,128 B (+pad row)
    unsigned short* ybf   = (unsigned short*)(ws + 12800512); // 12,800,128 B (+pad row, gathered)
    unsigned short* Wp    = (unsigned short*)(ws + 25601024); //    917,504 B (4 x 28 x 4096 x 2)
    int*            nbrsT = (int*)(ws + 26518528);            // 11,210,752 B (28 x 100096 x 4)
    float*          gpart = (float*)(ws + 37729280);          //      2,048 B (4 slots x 128)

    dim3 b256(256);
    hipMemsetAsync(gpart, 0, 4 * 128 * sizeof(float), stream);
    cast_in_k<<<((N_PTS + 1) * 8 + 255) / 256, b256, 0, stream>>>(feats, xb);
    tr_nbrs_k<<<NT_STRIDE / 64, b256, 0, stream>>>(nbrs, nbrsT);
    pack_w_k<<<(4 * NKP * 4096) / 256, b256, 0, stream>>>(W, Wp);

    const int appl_blocks = (TOTAL / 8) / 256;  // 3125
    for (int blk = 0; blk < 2; ++blk) {
        const int c0 = blk * 2, c1 = blk * 2 + 1;
        // conv c0: gathers final bf16 input xb -> raw ybf, stats -> slot c0
        conv_k<0><<<NB_CONV, b256, 0, stream>>>(
            xb, nbrsT, Wp + (size_t)c0 * NKP * 4096, ybf,
            nullptr, nullptr, nullptr, gpart + c0 * 128);
        // conv c1 (fused bn(c0)+relu on gather): raw ybf -> raw xb, stats -> slot c1
        conv_k<1><<<NB_CONV, b256, 0, stream>>>(
            ybf, nbrsT, Wp + (size_t)c1 * NKP * 4096, xb,
            gpart + c0 * 128, gamma + c0 * 64, beta + c0 * 64, gpart + c1 * 128);
        // bn(c1) + residual + relu: raw xb -> out (f32) and, for blk0, bf16 xb in-place
        const float* resp = (blk == 0) ? feats : (const float*)out;
        bn_fuse_k<<<appl_blocks, b256, 0, stream>>>(
            xb, gpart + c1 * 128, gamma + c1 * 64, beta + c1 * 64, resp, out, xb, blk == 0 ? 1 : 0);
    }
}

// Round 7
// 444.804 us; speedup vs baseline: 1.3324x; 1.3324x over previous
//
#include <hip/hip_runtime.h>

#define N_PTS 100000
#define NT_STRIDE 100096            // padded row count for nbrsT
#define NK 27
#define NKP 28                      // k slots incl. dummy zero slot k=27
#define TOTAL (N_PTS * 64)          // 6400000
#define NB_CONV 1564                // grid: 1564 blocks * 64 rows

typedef short bf16x8 __attribute__((ext_vector_type(8)));   // 8 bf16 in 4 VGPRs
typedef float f32x4 __attribute__((ext_vector_type(4)));
typedef unsigned short u16x8 __attribute__((ext_vector_type(8)));

__device__ __forceinline__ unsigned short f2bf(float f) {
    unsigned u = __builtin_bit_cast(unsigned, f);
    u += 0x7fffu + ((u >> 16) & 1u);           // round-to-nearest-even
    return (unsigned short)(u >> 16);
}
__device__ __forceinline__ float bf2f(unsigned short u) {
    return __builtin_bit_cast(float, ((unsigned)u) << 16);
}

// ---------------- cast feats -> bf16, plus zeroed pad row at index N_PTS ----------------
__global__ void cast_in_k(const float* __restrict__ feats, unsigned short* __restrict__ xb) {
    int t = blockIdx.x * 256 + threadIdx.x;
    if (t >= (N_PTS + 1) * 8) return;
    int i = t * 8;
    u16x8 o;
    if (i < TOTAL) {
        f32x4 v0 = ((const f32x4*)(feats + i))[0];
        f32x4 v1 = ((const f32x4*)(feats + i))[1];
#pragma unroll
        for (int j = 0; j < 4; ++j) { o[j] = f2bf(v0[j]); o[4 + j] = f2bf(v1[j]); }
    } else {
#pragma unroll
        for (int j = 0; j < 8; ++j) o[j] = 0;
    }
    *(u16x8*)(xb + i) = o;
}

// ---------------- transpose rulebook: nbrsT[k][n] = nbrs[n][k]; k=27 row & pad rows -> N_PTS ----------------
__global__ void tr_nbrs_k(const int* __restrict__ nbrs, int* __restrict__ nbrsT) {
    __shared__ int tile[64 * 28];
    const int n0 = blockIdx.x * 64;
    const int t = threadIdx.x;
    const int base = n0 * 27;
    for (int i = t; i < 1728; i += 256) {
        int v = (base + i < N_PTS * 27) ? nbrs[base + i] : N_PTS;
        int r = i / 27, c = i - r * 27;
        tile[r * 28 + c] = v;
    }
    __syncthreads();
    for (int i = t; i < 1728; i += 256) {
        int k = i >> 6, j = i & 63;                        // k 0..26
        nbrsT[(size_t)k * NT_STRIDE + n0 + j] = tile[j * 28 + k];
    }
    for (int i = t; i < 64; i += 256)                      // dummy k=27 row -> pad
        nbrsT[(size_t)27 * NT_STRIDE + n0 + i] = N_PTS;
}

// ---------------- pack W -> bf16 MFMA-B-fragment order, 28 k-slots/conv (k=27 zeroed) ----------------
// Wp layout: [conv][k(28)][kk][cb][lane][8]; frag elem j is B[c = kk*32+(lane>>4)*8+j, d = cb*16+(lane&15)]
__global__ void pack_w_k(const float* __restrict__ W, unsigned short* __restrict__ Wp) {
    int o = blockIdx.x * 256 + threadIdx.x;
    if (o >= 4 * NKP * 4096) return;
    int conv = o / (NKP * 4096);
    int r = o - conv * (NKP * 4096);
    int k = r >> 12;
    if (k == 27) { Wp[o] = 0; return; }
    int r2 = r & 4095;
    int frag = r2 >> 9;
    int kk = frag >> 2, cb = frag & 3;
    int lane = (r2 >> 3) & 63;
    int j = r2 & 7;
    int c = kk * 32 + (lane >> 4) * 8 + j;
    int d = cb * 16 + (lane & 15);
    Wp[o] = f2bf(W[(size_t)(conv * NK + k) * 4096 + c * 64 + d]);
}

// ---------------- gather-GEMM conv, coalesced gather via per-wave LDS row slab ----------------
// 4 waves/block = 2 rowhalves x 2 khalves (14 k-steps each; kh=1 includes zero dummy k=27).
// Gather: 8 consecutive lanes read one FULL 128B row (contiguous) -> per-wave LDS slab
// (144B row stride, bank-optimal b128), double-buffered; MFMA A-frags read from LDS.
#define SLAB_HW 72                  // halfwords per slab row (144 B)
#define SLAB_SZ (32 * SLAB_HW)      // one buffer: 32 rows
__global__ __launch_bounds__(256, 4) void conv_k(
    const unsigned short* __restrict__ xin,    // [N_PTS+1][64] bf16
    const int* __restrict__ nbrsT,             // [28][NT_STRIDE]
    const unsigned short* __restrict__ Wp,     // packed fragments for this conv (28 k-slots)
    unsigned short* __restrict__ yout,         // [N_PTS][64] bf16 raw conv output
    float* __restrict__ gpart_out)             // [128] accumulated sum/sumsq of yout
{
    const int tid = threadIdx.x;
    const int lane = tid & 63;
    const int wave = tid >> 6;
    const int l15 = lane & 15;
    const int lgrp = lane >> 4;
    const int oct = lane >> 3;                 // staging: octet 0..7 -> row within group of 8
    const int chk = lane & 7;                  // staging: 16B chunk within 128B row
    const int h = wave & 1;                    // rowhalf
    const int kh = wave >> 1;                  // khalf
    const int wave_row = blockIdx.x * 64 + h * 32;
    const int k0 = kh * 14;                    // kh=0: k 0..13 ; kh=1: k 14..27 (27 = zeros)

    // shared: per-wave double-buffered slabs; epilogue ytile aliases the same region
    __shared__ __align__(16) float smem[9216]; // 36,864 B
    __shared__ __align__(16) float sred[4][128];
    unsigned short* slab = (unsigned short*)smem + wave * (2 * SLAB_SZ);
    float* ytile = smem;                       // 64*68 = 4352 floats (aliased after barrier)

    f32x4 acc[2][4];
#pragma unroll
    for (int m = 0; m < 2; ++m)
#pragma unroll
        for (int cb = 0; cb < 4; ++cb) acc[m][cb] = (f32x4)0.f;

    const bf16x8* wp = (const bf16x8*)Wp;

    // ---- pipelined: idx window 1 step ahead of gather; gather 2 steps ahead of MFMA ----
    int idxP[4], idxN[4];
    bf16x8 gv[2][4];                           // in-flight gathered rows (16B/lane), 2 k-steps

#pragma unroll
    for (int i = 0; i < 4; ++i)
        idxP[i] = nbrsT[(size_t)k0 * NT_STRIDE + wave_row + i * 8 + oct];
#pragma unroll
    for (int i = 0; i < 4; ++i)
        idxN[i] = nbrsT[(size_t)(k0 + 1) * NT_STRIDE + wave_row + i * 8 + oct];
    // gather k-step 0, stage into buf0
#pragma unroll
    for (int i = 0; i < 4; ++i)
        gv[0][i] = *(const bf16x8*)(xin + (size_t)idxP[i] * 64 + chk * 8);
#pragma unroll
    for (int i = 0; i < 4; ++i)
        *(bf16x8*)(slab + (i * 8 + oct) * SLAB_HW + chk * 8) = gv[0][i];
    // gather k-step 1 into regs
#pragma unroll
    for (int i = 0; i < 4; ++i)
        gv[1][i] = *(const bf16x8*)(xin + (size_t)idxN[i] * 64 + chk * 8);

#pragma unroll
    for (int s = 0; s < 14; ++s) {
        // idx prefetch for s+2
        if (s + 2 < 14) {
#pragma unroll
            for (int i = 0; i < 4; ++i)
                idxP[i] = nbrsT[(size_t)(k0 + s + 2) * NT_STRIDE + wave_row + i * 8 + oct];
        }
        // stage data(s+1) into the other buffer (its old contents, data(s-1), already consumed)
        if (s + 1 < 14) {
#pragma unroll
            for (int i = 0; i < 4; ++i)
                *(bf16x8*)(slab + ((s + 1) & 1) * SLAB_SZ + (i * 8 + oct) * SLAB_HW + chk * 8) = gv[(s + 1) & 1][i];
        }
        // issue gather for s+2 into the register slot just freed
        if (s + 2 < 14) {
#pragma unroll
            for (int i = 0; i < 4; ++i)
                gv[s & 1][i] = *(const bf16x8*)(xin + (size_t)idxP[i] * 64 + chk * 8);
        }
        // read A-fragments of step s from LDS (bank-optimal: (row + lgrp) spreads over 8 groups)
        const unsigned short* sb = slab + (s & 1) * SLAB_SZ;
        bf16x8 a00 = *(const bf16x8*)(sb + l15 * SLAB_HW + lgrp * 8);
        bf16x8 a01 = *(const bf16x8*)(sb + l15 * SLAB_HW + 32 + lgrp * 8);
        bf16x8 a10 = *(const bf16x8*)(sb + (16 + l15) * SLAB_HW + lgrp * 8);
        bf16x8 a11 = *(const bf16x8*)(sb + (16 + l15) * SLAB_HW + 32 + lgrp * 8);

        const bf16x8* wk = wp + (size_t)(k0 + s) * 512 + lane;
        {   // kk = 0 (c 0..31)
            bf16x8 b0 = wk[0], b1 = wk[64], b2 = wk[128], b3 = wk[192];
            acc[0][0] = __builtin_amdgcn_mfma_f32_16x16x32_bf16(a00, b0, acc[0][0], 0, 0, 0);
            acc[1][0] = __builtin_amdgcn_mfma_f32_16x16x32_bf16(a10, b0, acc[1][0], 0, 0, 0);
            acc[0][1] = __builtin_amdgcn_mfma_f32_16x16x32_bf16(a00, b1, acc[0][1], 0, 0, 0);
            acc[1][1] = __builtin_amdgcn_mfma_f32_16x16x32_bf16(a10, b1, acc[1][1], 0, 0, 0);
            acc[0][2] = __builtin_amdgcn_mfma_f32_16x16x32_bf16(a00, b2, acc[0][2], 0, 0, 0);
            acc[1][2] = __builtin_amdgcn_mfma_f32_16x16x32_bf16(a10, b2, acc[1][2], 0, 0, 0);
            acc[0][3] = __builtin_amdgcn_mfma_f32_16x16x32_bf16(a00, b3, acc[0][3], 0, 0, 0);
            acc[1][3] = __builtin_amdgcn_mfma_f32_16x16x32_bf16(a10, b3, acc[1][3], 0, 0, 0);
        }
        {   // kk = 1 (c 32..63)
            bf16x8 b0 = wk[256], b1 = wk[320], b2 = wk[384], b3 = wk[448];
            acc[0][0] = __builtin_amdgcn_mfma_f32_16x16x32_bf16(a01, b0, acc[0][0], 0, 0, 0);
            acc[1][0] = __builtin_amdgcn_mfma_f32_16x16x32_bf16(a11, b0, acc[1][0], 0, 0, 0);
            acc[0][1] = __builtin_amdgcn_mfma_f32_16x16x32_bf16(a01, b1, acc[0][1], 0, 0, 0);
            acc[1][1] = __builtin_amdgcn_mfma_f32_16x16x32_bf16(a11, b1, acc[1][1], 0, 0, 0);
            acc[0][2] = __builtin_amdgcn_mfma_f32_16x16x32_bf16(a01, b2, acc[0][2], 0, 0, 0);
            acc[1][2] = __builtin_amdgcn_mfma_f32_16x16x32_bf16(a11, b2, acc[1][2], 0, 0, 0);
            acc[0][3] = __builtin_amdgcn_mfma_f32_16x16x32_bf16(a01, b3, acc[0][3], 0, 0, 0);
            acc[1][3] = __builtin_amdgcn_mfma_f32_16x16x32_bf16(a11, b3, acc[1][3], 0, 0, 0);
        }
    }

    // ---- all waves done with slabs before ytile aliases them ----
    __syncthreads();

    // ---- K-half reduction through LDS f32 tile (row stride 68 keeps 16B alignment) ----
    if (kh == 0) {
#pragma unroll
        for (int m = 0; m < 2; ++m)
#pragma unroll
            for (int cb = 0; cb < 4; ++cb)
#pragma unroll
                for (int r = 0; r < 4; ++r)
                    ytile[(h * 32 + m * 16 + lgrp * 4 + r) * 68 + cb * 16 + l15] = acc[m][cb][r];
    }
    __syncthreads();
    if (kh == 1) {
#pragma unroll
        for (int m = 0; m < 2; ++m)
#pragma unroll
            for (int cb = 0; cb < 4; ++cb)
#pragma unroll
                for (int r = 0; r < 4; ++r)
                    ytile[(h * 32 + m * 16 + lgrp * 4 + r) * 68 + cb * 16 + l15] += acc[m][cb][r];
    }
    __syncthreads();

    // ---- coalesced read-out -> bf16 y store + per-channel sum/sumsq ----
    const int row = tid >> 2;                  // 0..63
    const int colb = (tid & 3) * 16;           // 0,16,32,48
    f32x4 v[4];
#pragma unroll
    for (int j = 0; j < 4; ++j) v[j] = *(const f32x4*)&ytile[row * 68 + colb + 4 * j];

    const int grow = blockIdx.x * 64 + row;
    if (grow < N_PTS) {
        u16x8 o0, o1;
#pragma unroll
        for (int j = 0; j < 4; ++j) { o0[j] = f2bf(v[0][j]); o0[4 + j] = f2bf(v[1][j]); }
#pragma unroll
        for (int j = 0; j < 4; ++j) { o1[j] = f2bf(v[2][j]); o1[4 + j] = f2bf(v[3][j]); }
        *(u16x8*)(yout + (size_t)grow * 64 + colb) = o0;
        *(u16x8*)(yout + (size_t)grow * 64 + colb + 8) = o1;
    }

    f32x4 sv[4], s2v[4];
#pragma unroll
    for (int j = 0; j < 4; ++j) { sv[j] = v[j]; s2v[j] = v[j] * v[j]; }
#pragma unroll
    for (int off = 4; off < 64; off <<= 1) {
#pragma unroll
        for (int j = 0; j < 4; ++j) {
#pragma unroll
            for (int e = 0; e < 4; ++e) {
                sv[j][e]  += __shfl_xor(sv[j][e],  off);
                s2v[j][e] += __shfl_xor(s2v[j][e], off);
            }
        }
    }
    if (lane < 4) {
#pragma unroll
        for (int j = 0; j < 4; ++j) {
            *(f32x4*)&sred[wave][lane * 16 + 4 * j]      = sv[j];
            *(f32x4*)&sred[wave][64 + lane * 16 + 4 * j] = s2v[j];
        }
    }
    __syncthreads();
    if (tid < 128) {
        float p = sred[0][tid] + sred[1][tid] + sred[2][tid] + sred[3][tid];
        atomicAdd(&gpart_out[tid], p);
    }
}

// ---------------- BN(inline stats) + ReLU -> bf16 (input to next conv) ----------------
__global__ void bn_relu_cast_k(const unsigned short* __restrict__ yraw,
                               const float* __restrict__ gpart,
                               const float* __restrict__ gamma,
                               const float* __restrict__ beta,
                               unsigned short* __restrict__ xb) {
    int t = blockIdx.x * 256 + threadIdx.x;
    if (t >= TOTAL / 8) return;
    int i = t * 8;
    int c0 = i & 63;
    u16x8 v = *(const u16x8*)(yraw + i);
    const float invN = 1.0f / (float)N_PTS;
    u16x8 o;
#pragma unroll
    for (int j = 0; j < 8; ++j) {
        int c = c0 + j;
        float S = gpart[c], S2 = gpart[64 + c];
        float mu = S * invN;
        float var = S2 * invN - mu * mu;
        float s = gamma[c] * rsqrtf(var + 1e-4f);
        o[j] = f2bf(fmaxf(bf2f(v[j]) * s + (beta[c] - mu * s), 0.f));
    }
    *(u16x8*)(xb + i) = o;
}

// ---------------- BN(inline stats) + residual + ReLU -> f32 out (+ bf16 for next conv) ----------------
__global__ void bn_add_relu_k(const unsigned short* __restrict__ yraw,
                              const float* __restrict__ gpart,
                              const float* __restrict__ gamma,
                              const float* __restrict__ beta,
                              const float* __restrict__ res,
                              float* __restrict__ xout,
                              unsigned short* __restrict__ xb, int writeBf) {
    int t = blockIdx.x * 256 + threadIdx.x;
    if (t >= TOTAL / 8) return;
    int i = t * 8;
    int c0 = i & 63;
    u16x8 v = *(const u16x8*)(yraw + i);
    f32x4 q0 = ((const f32x4*)(res + i))[0];
    f32x4 q1 = ((const f32x4*)(res + i))[1];
    const float invN = 1.0f / (float)N_PTS;
    float ov[8];
#pragma unroll
    for (int j = 0; j < 8; ++j) {
        int c = c0 + j;
        float S = gpart[c], S2 = gpart[64 + c];
        float mu = S * invN;
        float var = S2 * invN - mu * mu;
        float s = gamma[c] * rsqrtf(var + 1e-4f);
        float q = (j < 4) ? q0[j] : q1[j - 4];
        ov[j] = fmaxf(bf2f(v[j]) * s + (beta[c] - mu * s) + q, 0.f);
    }
    f32x4 o0, o1;
#pragma unroll
    for (int j = 0; j < 4; ++j) { o0[j] = ov[j]; o1[j] = ov[4 + j]; }
    ((f32x4*)(xout + i))[0] = o0;
    ((f32x4*)(xout + i))[1] = o1;
    if (writeBf) {
        u16x8 o;
#pragma unroll
        for (int j = 0; j < 8; ++j) o[j] = f2bf(ov[j]);
        *(u16x8*)(xb + i) = o;
    }
}

extern "C" void kernel_launch(void* const* d_in, const int* in_sizes, int n_in,
                              void* d_out, int out_size, void* d_ws, size_t ws_size,
                              hipStream_t stream) {
    const float* feats = (const float*)d_in[0];
    const int*   nbrs  = (const int*)d_in[1];
    const float* W     = (const float*)d_in[2];
    const float* gamma = (const float*)d_in[3];
    const float* beta  = (const float*)d_in[4];
    float* out = (float*)d_out;

    char* ws = (char*)d_ws;
    unsigned short* xb    = (unsigned short*)ws;              // 12,800,128 B (+pad row)
    unsigned short* ybf   = (unsigned short*)(ws + 12800512); // 12,800,000 B
    unsigned short* Wp    = (unsigned short*)(ws + 25600512); //    917,504 B (4 x 28 x 4096 x 2)
    int*            nbrsT = (int*)(ws + 26518016);            // 11,210,752 B (28 x 100096 x 4)
    float*          gpart = (float*)(ws + 37728768);          //      2,048 B (4 slots x 128)

    dim3 b256(256);
    hipMemsetAsync(gpart, 0, 4 * 128 * sizeof(float), stream);
    cast_in_k<<<((N_PTS + 1) * 8 + 255) / 256, b256, 0, stream>>>(feats, xb);
    tr_nbrs_k<<<NT_STRIDE / 64, b256, 0, stream>>>(nbrs, nbrsT);
    pack_w_k<<<(4 * NKP * 4096) / 256, b256, 0, stream>>>(W, Wp);

    const int appl_blocks = (TOTAL / 8) / 256;  // 3125
    for (int blk = 0; blk < 2; ++blk) {
        const int c0 = blk * 2, c1 = blk * 2 + 1;
        conv_k<<<NB_CONV, b256, 0, stream>>>(
            xb, nbrsT, Wp + (size_t)c0 * NKP * 4096, ybf, gpart + c0 * 128);
        bn_relu_cast_k<<<appl_blocks, b256, 0, stream>>>(
            ybf, gpart + c0 * 128, gamma + c0 * 64, beta + c0 * 64, xb);
        conv_k<<<NB_CONV, b256, 0, stream>>>(
            xb, nbrsT, Wp + (size_t)c1 * NKP * 4096, ybf, gpart + c1 * 128);
        const float* resp = (blk == 0) ? feats : (const float*)out;
        bn_add_relu_k<<<appl_blocks, b256, 0, stream>>>(
            ybf, gpart + c1 * 128, gamma + c1 * 64, beta + c1 * 64, resp, out, xb, blk == 0 ? 1 : 0);
    }
}